// Round 2
// baseline (323.636 us; speedup 1.0000x reference)
//
#include <hip/hip_runtime.h>
#include <math.h>

#define N_NODES 50000
#define N_EDGES 600000
#define F 128
#define NT 4
#define NKTG 20                // K tiles of 32 (640/32)
#define NCT 8                  // out-col tiles of 16 (128/16)
#define N_SEG (NT * N_NODES)   // 200000
#define SCAN_BLK 196           // ceil(N_SEG / 1024)
#define WELEM (NKTG * NCT * 64 * 8)  // 81920 fp16 elements per layer
#define PW_CAP 128             // per-wave perm-queue capacity (entries)

typedef __attribute__((ext_vector_type(8))) _Float16 f16x8;
typedef __attribute__((ext_vector_type(4))) float f32x4;

__device__ __forceinline__ unsigned short f2h(float f) {
    _Float16 h = (_Float16)f;
    return __builtin_bit_cast(unsigned short, h);
}
__device__ __forceinline__ float h2f(unsigned short u) {
    return (float)__builtin_bit_cast(_Float16, u);
}
__device__ __forceinline__ unsigned pack2h(float a, float b) {
    return (unsigned)f2h(a) | ((unsigned)f2h(b) << 16);
}

// ---- build combined weights B[640,128] per layer, fp16 hi/lo, MFMA-frag order ----
__global__ __launch_bounds__(256) void build_w(
    const float* __restrict__ Ws1, const float* __restrict__ Wn1, const float* __restrict__ b1,
    const float* __restrict__ Ws2, const float* __restrict__ Wn2, const float* __restrict__ b2,
    unsigned short* __restrict__ Wh, unsigned short* __restrict__ Wl,
    float* __restrict__ bavg)
{
    int idx = blockIdx.x * 256 + threadIdx.x;
    const int perLayer = NKTG * NCT * 64;   // 10240 fragments
    if (idx < 2 * perLayer) {
        int l = idx >= perLayer;
        int rem = idx - l * perLayer;
        int lane = rem & 63;
        int ct = (rem >> 6) & 7;
        int ktg = (rem >> 6) >> 3;
        const float* Wsl = l ? Ws2 : Ws1;
        const float* Wnl = l ? Wn2 : Wn1;
        unsigned short* oh = Wh + (size_t)l * WELEM + (size_t)rem * 8;
        unsigned short* ol = Wl + (size_t)l * WELEM + (size_t)rem * 8;
        int c = ct * 16 + (lane & 15);
        int kb = ktg * 32 + (lane >> 4) * 8;
#pragma unroll
        for (int j = 0; j < 8; ++j) {
            int k = kb + j;
            float v;
            if (k < F) {
                v = 0.25f * (Wsl[(0 * F + k) * F + c] + Wsl[(1 * F + k) * F + c] +
                             Wsl[(2 * F + k) * F + c] + Wsl[(3 * F + k) * F + c]);
            } else {
                int t = (k - F) >> 7;
                int kk = (k - F) & (F - 1);
                v = 0.25f * Wnl[((size_t)t * F + kk) * F + c];
            }
            _Float16 hh = (_Float16)v;
            oh[j] = __builtin_bit_cast(unsigned short, hh);
            ol[j] = f2h(v - (float)hh);
        }
    } else {
        int k = idx - 2 * perLayer;
        if (k < 2 * F) {
            int l = k >> 7;
            int j = k & (F - 1);
            const float* bl = l ? b2 : b1;
            bavg[k] = 0.25f * (bl[j] + bl[F + j] + bl[2 * F + j] + bl[3 * F + j]);
        }
    }
}

// ---- cast x fp32 -> fp16 ----
__global__ __launch_bounds__(256) void cast_x(
    const float* __restrict__ x, unsigned short* __restrict__ x16)
{
    int i = blockIdx.x * 256 + threadIdx.x;
    if (i < N_NODES * 64) {
        float2 v = ((const float2*)x)[i];
        ((unsigned*)x16)[i] = pack2h(v.x, v.y);
    }
}

// ---------------- CSR build: seg = dst*4 + t ----------------
__global__ __launch_bounds__(256) void hist_kernel(
    const int* __restrict__ dstA, const int* __restrict__ typA, int* __restrict__ counts)
{
    int e = blockIdx.x * 256 + threadIdx.x;
    if (e < N_EDGES) atomicAdd(&counts[dstA[e] * NT + typA[e]], 1);
}

__global__ __launch_bounds__(256) void scan1(int* __restrict__ counts, int* __restrict__ bsum)
{
    __shared__ int sh[256];
    int t = threadIdx.x;
    int base = blockIdx.x * 1024 + t * 4;
    int v[4];
    int tot = 0;
#pragma unroll
    for (int j = 0; j < 4; ++j) {
        int i = base + j;
        v[j] = (i < N_SEG) ? counts[i] : 0;
        tot += v[j];
    }
    sh[t] = tot;
    __syncthreads();
    for (int ofs = 1; ofs < 256; ofs <<= 1) {
        int add = (t >= ofs) ? sh[t - ofs] : 0;
        __syncthreads();
        sh[t] += add;
        __syncthreads();
    }
    int excl = (t > 0) ? sh[t - 1] : 0;
    if (t == 255) bsum[blockIdx.x] = sh[255];
#pragma unroll
    for (int j = 0; j < 4; ++j) {
        int i = base + j;
        if (i < N_SEG) counts[i] = excl;
        excl += v[j];
    }
}

__global__ __launch_bounds__(256) void scan2(int* __restrict__ bsum)
{
    __shared__ int sh[256];
    int t = threadIdx.x;
    sh[t] = (t < SCAN_BLK) ? bsum[t] : 0;
    __syncthreads();
    for (int ofs = 1; ofs < 256; ofs <<= 1) {
        int add = (t >= ofs) ? sh[t - ofs] : 0;
        __syncthreads();
        sh[t] += add;
        __syncthreads();
    }
    int excl = (t > 0) ? sh[t - 1] : 0;
    if (t < SCAN_BLK) bsum[t] = excl;
}

// finalize offsets in place; pad tail [N_SEG, N_SEG+256) with N_EDGES so the
// fused kernel's 64-lane boundary loads past the last node read empty segments
__global__ __launch_bounds__(256) void scan3(
    int* __restrict__ counts, const int* __restrict__ bsum, int* __restrict__ cursor)
{
    int i = blockIdx.x * 256 + threadIdx.x;
    if (i < N_SEG) {
        int v = counts[i] + bsum[i >> 10];
        counts[i] = v;
        cursor[i] = v;
    } else if (i < N_SEG + 256) {
        counts[i] = N_EDGES;
    }
}

// permute: bucket-sorted edge list; payload = (src << 2) | type
__global__ __launch_bounds__(256) void permute_kernel(
    const int* __restrict__ srcA, const int* __restrict__ dstA, const int* __restrict__ typA,
    int* __restrict__ cursor, unsigned* __restrict__ perm)
{
    int e = blockIdx.x * 256 + threadIdx.x;
    if (e < N_EDGES) {
        int t = typA[e];
        int seg = dstA[e] * NT + t;
        int pos = atomicAdd(&cursor[seg], 1);
        perm[pos] = ((unsigned)srcA[e] << 2) | (unsigned)t;
    }
}

// ---- lane-vector helpers for the fused kernel ----
// vo holds off[] boundaries lane-indexed: lane i*4+t = start of (node i, type t).
// Counts are clamped to 64 (P(Poisson(3) > 64) ~ 1e-80 for this dataset).
#define COMPUTE_TYPE(T, SV, CV, PV, EW) do { \
    int srcI_ = (lane < 8 ? lane : 7) * 4 + (T); \
    SV = __shfl(vo, srcI_); \
    int ev_ = __shfl(vo, srcI_ + 1); \
    CV = ev_ - SV; if (CV < 0) CV = 0; if (CV > 64) CV = 64; \
    int pz_ = (lane < 8) ? CV : 0; \
    int ac_ = pz_; \
    int t1_ = __shfl_up(ac_, 1); if (lane >= 1) ac_ += t1_; \
    int t2_ = __shfl_up(ac_, 2); if (lane >= 2) ac_ += t2_; \
    int t4_ = __shfl_up(ac_, 4); if (lane >= 4) ac_ += t4_; \
    PV = ac_ - pz_; \
    EW = __builtin_amdgcn_readfirstlane(__shfl(ac_, 7)); \
    if (EW > PW_CAP) EW = PW_CAP; \
} while (0)

#define ISSUE_PKV(SV, PK) do { \
    _Pragma("unroll") \
    for (int i_ = 0; i_ < 8; ++i_) { \
        int s_ = __builtin_amdgcn_readlane(SV, i_); \
        int p_ = s_ + lane; \
        p_ = p_ < N_EDGES ? p_ : N_EDGES - 1; \
        PK[i_] = perm[p_]; \
    } \
} while (0)

// entry = (src << 4) | (node_i << 1) | last_edge_flag
#define COMPACT(CV, PV, PK, PWP) do { \
    _Pragma("unroll") \
    for (int i_ = 0; i_ < 8; ++i_) { \
        int c_ = __builtin_amdgcn_readlane(CV, i_); \
        int p_ = __builtin_amdgcn_readlane(PV, i_); \
        if (lane < c_ && p_ + lane < PW_CAP) { \
            unsigned e_ = ((PK[i_] & ~3u) << 2) | ((unsigned)i_ << 1) | (unsigned)(lane == c_ - 1); \
            PWP[p_ + lane] = e_; \
        } \
    } \
} while (0)

// ---- fused layer: out[N,128] = [H | mean_t(H[src])] @ B[640,128] (+bias, epilogue)
// block = 32 nodes, 4 waves; wave w aggregates nodes w*8..w*8+7 per type-chunk,
// staging means directly into the LDS A-tile between MFMA chunks.
__global__ __launch_bounds__(256) void fused_layer(
    const unsigned short* __restrict__ Hin,   // [N,128] fp16 (self + gather source)
    const unsigned* __restrict__ perm,
    const int* __restrict__ off,              // [N_SEG+256], tail = N_EDGES
    const unsigned short* __restrict__ Wh,    // frag-ordered fp16 hi (this layer)
    const unsigned short* __restrict__ Wl,    // frag-ordered fp16 lo
    const float* __restrict__ bias,           // 128 fp32
    float* __restrict__ outF,                 // fp32 output (layer 2)
    unsigned short* __restrict__ outH,        // fp16 output (layer 1, norm+relu)
    int doNormRelu)
{
    __shared__ unsigned short AS[32][136];    // A chunk (K=128 slice), padded pitch
    __shared__ unsigned Pw[4][PW_CAP];        // per-wave compacted perm queue
    __shared__ float rs[32][4];               // row sumsq partials (L1 epilogue)

    const int tid = threadIdx.x;
    const int lane = tid & 63;
    const int w = tid >> 6;
    const int quad = lane >> 4;
    const int l15 = lane & 15;
    const int nodeBase = blockIdx.x * 32;
    const unsigned* Hg = (const unsigned*)Hin;
    unsigned* PwW = Pw[w];

    // ---- prologue: boundary vector + H-chunk staging + type-0 perm prefetch ----
    const int n0w4 = (nodeBase + w * 8) * 4;
    int vo = off[n0w4 + lane];                // 33 boundaries (8 nodes x 4 types + end)

    {
        int row = tid >> 3;
        int cb = (tid & 7) * 16;
        int n = nodeBase + row;
        int nc = n < N_NODES ? n : N_NODES - 1;
        const uint4* s0 = (const uint4*)(Hin + (size_t)nc * F + cb);
        uint4 a = s0[0], b = s0[1];
        *(uint4*)&AS[row][cb] = a;
        *(uint4*)&AS[row][cb + 8] = b;
    }

    int svC, cvC, pvC, EwC;
    COMPUTE_TYPE(0, svC, cvC, pvC, EwC);
    unsigned pkv[8];
    ISSUE_PKV(svC, pkv);

    __syncthreads();                          // drain H staging + vo + pkv(type0)

    COMPACT(cvC, pvC, pkv, PwW);

    f32x4 acc[2][2];
#pragma unroll
    for (int rt = 0; rt < 2; ++rt)
#pragma unroll
        for (int ci = 0; ci < 2; ++ci)
            acc[rt][ci] = (f32x4){0.f, 0.f, 0.f, 0.f};

    const f16x8* BH = (const f16x8*)Wh;
    const f16x8* BL = (const f16x8*)Wl;

    int svN, cvN, pvN, EwN = 0;
    unsigned uv[32];
    int nb0 = 0;

#pragma unroll 1
    for (int kc = 0; kc < 5; ++kc) {
        // ---- prep: B frags FIRST (so their wait doesn't drain gathers) ----
        f16x8 bh[4][2], bl[4][2];
#pragma unroll
        for (int kt = 0; kt < 4; ++kt)
#pragma unroll
            for (int ci = 0; ci < 2; ++ci) {
                int fi = ((kc * 4 + kt) * NCT + (w * 2 + ci)) * 64 + lane;
                bh[kt][ci] = BH[fi];
                bl[kt][ci] = BL[fi];
            }
        __builtin_amdgcn_sched_barrier(0);

        if (kc < 4) {
            // issue this type's gathers (deep pipeline, consumed after the MFMA)
            nb0 = EwC < 32 ? EwC : 32;
#pragma unroll
            for (int sj = 0; sj < 32; ++sj) {
                if (sj < nb0) {
                    unsigned ent = PwW[sj];
                    uv[sj] = Hg[(ent >> 4) * 64 + lane];
                }
            }
            if (kc < 3) {                     // prefetch next type's perm entries
                COMPUTE_TYPE(kc + 1, svN, cvN, pvN, EwN);
                ISSUE_PKV(svN, pkv);
            }
            __builtin_amdgcn_sched_barrier(0);
        }

        // ---- MFMA chunk kc (gathers in flight) ----
#pragma unroll
        for (int kt = 0; kt < 4; ++kt) {
            f16x8 ah[2];
#pragma unroll
            for (int rt = 0; rt < 2; ++rt)
                ah[rt] = *(const f16x8*)&AS[rt * 16 + l15][kt * 32 + quad * 8];
#pragma unroll
            for (int rt = 0; rt < 2; ++rt)
#pragma unroll
                for (int ci = 0; ci < 2; ++ci) {
                    acc[rt][ci] = __builtin_amdgcn_mfma_f32_16x16x32_f16(ah[rt], bh[kt][ci], acc[rt][ci], 0, 0, 0);
                    acc[rt][ci] = __builtin_amdgcn_mfma_f32_16x16x32_f16(ah[rt], bl[kt][ci], acc[rt][ci], 0, 0, 0);
                }
        }

        if (kc < 4) {
            __syncthreads();                  // AS free; gathers + pkv drained

            // zero rows for empty segments (incl. padding nodes)
#pragma unroll
            for (int i = 0; i < 8; ++i)
                if (__builtin_amdgcn_readlane(cvC, i) == 0)
                    ((unsigned*)&AS[w * 8 + i][0])[lane] = 0;

            // accumulate slots in node order; entry's last-flag drives flushes
            float ax = 0.f, ay = 0.f;
#pragma unroll
            for (int sj = 0; sj < 32; ++sj) {
                if (sj < nb0) {
                    unsigned ent = PwW[sj];
                    unsigned u = uv[sj];
                    ax += h2f((unsigned short)(u & 0xffffu));
                    ay += h2f((unsigned short)(u >> 16));
                    if (ent & 1u) {
                        int i = (int)((ent >> 1) & 7u);
                        float inv = 1.0f / fmaxf((float)__builtin_amdgcn_readlane(cvC, i), 1.0f);
                        ((unsigned*)&AS[w * 8 + i][0])[lane] = pack2h(ax * inv, ay * inv);
                        ax = 0.f; ay = 0.f;
                    }
                }
            }
            // rare overflow batches (E_w > 32, ~5%)
            for (int bb = 32; bb < EwC; bb += 32) {
                int nb = (EwC - bb) < 32 ? (EwC - bb) : 32;
#pragma unroll
                for (int sj = 0; sj < 32; ++sj) {
                    if (sj < nb) {
                        unsigned ent = PwW[bb + sj];
                        unsigned u = Hg[(ent >> 4) * 64 + lane];
                        ax += h2f((unsigned short)(u & 0xffffu));
                        ay += h2f((unsigned short)(u >> 16));
                        if (ent & 1u) {
                            int i = (int)((ent >> 1) & 7u);
                            float inv = 1.0f / fmaxf((float)__builtin_amdgcn_readlane(cvC, i), 1.0f);
                            ((unsigned*)&AS[w * 8 + i][0])[lane] = pack2h(ax * inv, ay * inv);
                            ax = 0.f; ay = 0.f;
                        }
                    }
                }
            }

            if (kc < 3) {                     // queue next type's entries
                COMPACT(cvN, pvN, pkv, PwW);
                svC = svN; cvC = cvN; pvC = pvN; EwC = EwN;
            }
            __syncthreads();                  // AS staged for chunk kc+1
        }
    }

    // ---- epilogue ----
    float bv0 = bias[w * 32 + l15];
    float bv1 = bias[w * 32 + 16 + l15];

    if (doNormRelu) {
#pragma unroll
        for (int rt = 0; rt < 2; ++rt)
#pragma unroll
            for (int rr = 0; rr < 4; ++rr) {
                float vx = acc[rt][0][rr] + bv0;
                float vy = acc[rt][1][rr] + bv1;
                float s = vx * vx + vy * vy;
                s += __shfl_xor(s, 1);
                s += __shfl_xor(s, 2);
                s += __shfl_xor(s, 4);
                s += __shfl_xor(s, 8);
                if (l15 == 0) rs[rt * 16 + quad * 4 + rr][w] = s;
            }
        __syncthreads();
#pragma unroll
        for (int rt = 0; rt < 2; ++rt)
#pragma unroll
            for (int rr = 0; rr < 4; ++rr) {
                int row = rt * 16 + quad * 4 + rr;
                int nn = nodeBase + row;
                if (nn < N_NODES) {
                    float tot = rs[row][0] + rs[row][1] + rs[row][2] + rs[row][3];
                    float sc = 1.0f / fmaxf(sqrtf(tot), 1e-12f);
                    float vx = fmaxf((acc[rt][0][rr] + bv0) * sc, 0.f);
                    float vy = fmaxf((acc[rt][1][rr] + bv1) * sc, 0.f);
                    outH[(size_t)nn * F + w * 32 + l15]      = f2h(vx);
                    outH[(size_t)nn * F + w * 32 + 16 + l15] = f2h(vy);
                }
            }
    } else {
#pragma unroll
        for (int rt = 0; rt < 2; ++rt)
#pragma unroll
            for (int rr = 0; rr < 4; ++rr) {
                int nn = nodeBase + rt * 16 + quad * 4 + rr;
                if (nn < N_NODES) {
                    float* o = outF + (size_t)nn * F + w * 32 + l15;
                    o[0]  = acc[rt][0][rr] + bv0;
                    o[16] = acc[rt][1][rr] + bv1;
                }
            }
    }
}

extern "C" void kernel_launch(void* const* d_in, const int* in_sizes, int n_in,
                              void* d_out, int out_size, void* d_ws, size_t ws_size,
                              hipStream_t stream)
{
    const float* x   = (const float*)d_in[0];
    const float* Ws1 = (const float*)d_in[1];
    const float* Wn1 = (const float*)d_in[2];
    const float* b1  = (const float*)d_in[3];
    const float* Ws2 = (const float*)d_in[4];
    const float* Wn2 = (const float*)d_in[5];
    const float* b2  = (const float*)d_in[6];
    const int* edge_index = (const int*)d_in[7];
    const int* edge_type  = (const int*)d_in[8];

    const int* srcA = edge_index;
    const int* dstA = edge_index + N_EDGES;

    // workspace layout
    unsigned short* x16 = (unsigned short*)d_ws;             // N*128 u16 = 12.8 MB
    unsigned short* h1  = x16 + (size_t)N_NODES * F;         // N*128 u16 = 12.8 MB
    unsigned short* Wh  = h1 + (size_t)N_NODES * F;          // 2*WELEM u16
    unsigned short* Wl  = Wh + (size_t)2 * WELEM;            // 2*WELEM u16
    float* bavg = (float*)(Wl + (size_t)2 * WELEM);          // 256 f32
    int* counts = (int*)(bavg + 2 * F);                      // N_SEG + 256 (off + padded tail)
    int* cursor = counts + (N_SEG + 256);                    // N_SEG
    int* bsum   = cursor + N_SEG;                            // 256
    unsigned* perm = (unsigned*)(bsum + 256);                // N_EDGES u32 = 2.4 MB
    int* off = counts;                                       // alias after scan3

    // weights + bias + fp16 cast of x
    hipLaunchKernelGGL(build_w, dim3(81), dim3(256), 0, stream,
                       Ws1, Wn1, b1, Ws2, Wn2, b2, Wh, Wl, bavg);
    hipLaunchKernelGGL(cast_x, dim3((N_NODES * 64 + 255) / 256), dim3(256), 0, stream,
                       x, x16);

    // CSR build (shared by both layers)
    hipMemsetAsync(counts, 0, (size_t)N_SEG * sizeof(int), stream);
    hipLaunchKernelGGL(hist_kernel, dim3((N_EDGES + 255) / 256), dim3(256), 0, stream,
                       dstA, edge_type, counts);
    hipLaunchKernelGGL(scan1, dim3(SCAN_BLK), dim3(256), 0, stream, counts, bsum);
    hipLaunchKernelGGL(scan2, dim3(1), dim3(256), 0, stream, bsum);
    hipLaunchKernelGGL(scan3, dim3((N_SEG + 256 + 255) / 256), dim3(256), 0, stream,
                       counts, bsum, cursor);
    hipLaunchKernelGGL(permute_kernel, dim3((N_EDGES + 255) / 256), dim3(256), 0, stream,
                       srcA, dstA, edge_type, cursor, perm);

    const int fusedGrid = (N_NODES + 31) / 32;    // 1563

    // ---------- layer 1 ----------
    hipLaunchKernelGGL(fused_layer, dim3(fusedGrid), dim3(256), 0, stream,
                       x16, perm, off, Wh, Wl, bavg,
                       (float*)nullptr, h1, 1);

    // ---------- layer 2 ----------
    hipLaunchKernelGGL(fused_layer, dim3(fusedGrid), dim3(256), 0, stream,
                       h1, perm, off, Wh + WELEM, Wl + WELEM, bavg + F,
                       (float*)d_out, (unsigned short*)nullptr, 0);
}

// Round 3
// 298.399 us; speedup vs baseline: 1.0846x; 1.0846x over previous
//
#include <hip/hip_runtime.h>
#include <math.h>

#define N_NODES 50000
#define N_EDGES 600000
#define F 128
#define NT 4
#define NKTG 20                // K tiles of 32 (640 total K over 5 planes)
#define NCT 8                  // out-col tiles of 16 (128/16)
#define N_SEG (NT * N_NODES)   // 200000
#define SCAN_BLK 196           // ceil(N_SEG / 1024)
#define WELEM (NKTG * NCT * 64 * 8)  // 81920 fp16 elements per layer

typedef __attribute__((ext_vector_type(8))) _Float16 f16x8;
typedef __attribute__((ext_vector_type(4))) float f32x4;

__device__ __forceinline__ unsigned short f2h(float f) {
    _Float16 h = (_Float16)f;
    return __builtin_bit_cast(unsigned short, h);
}
__device__ __forceinline__ unsigned pack2h(float a, float b) {
    return (unsigned)f2h(a) | ((unsigned)f2h(b) << 16);
}
__device__ __forceinline__ unsigned short f2b(float f) {   // fp32 -> bf16 RNE
    unsigned u = __float_as_uint(f);
    return (unsigned short)((u + 0x7FFFu + ((u >> 16) & 1u)) >> 16);
}

// ---- build combined weights B[640,128] per layer, fp16 hi/lo, MFMA-frag order ----
// K rows 0..127 = 0.25*sum_t Ws[t] (self); rows 128+t*128.. = 0.25*Wn[t]
__global__ __launch_bounds__(256) void build_w(
    const float* __restrict__ Ws1, const float* __restrict__ Wn1, const float* __restrict__ b1,
    const float* __restrict__ Ws2, const float* __restrict__ Wn2, const float* __restrict__ b2,
    unsigned short* __restrict__ Wh, unsigned short* __restrict__ Wl,
    float* __restrict__ bavg)
{
    int idx = blockIdx.x * 256 + threadIdx.x;
    const int perLayer = NKTG * NCT * 64;   // 10240 fragments
    if (idx < 2 * perLayer) {
        int l = idx >= perLayer;
        int rem = idx - l * perLayer;
        int lane = rem & 63;
        int ct = (rem >> 6) & 7;
        int ktg = (rem >> 6) >> 3;
        const float* Wsl = l ? Ws2 : Ws1;
        const float* Wnl = l ? Wn2 : Wn1;
        unsigned short* oh = Wh + (size_t)l * WELEM + (size_t)rem * 8;
        unsigned short* ol = Wl + (size_t)l * WELEM + (size_t)rem * 8;
        int c = ct * 16 + (lane & 15);
        int kb = ktg * 32 + (lane >> 4) * 8;
#pragma unroll
        for (int j = 0; j < 8; ++j) {
            int k = kb + j;
            float v;
            if (k < F) {
                v = 0.25f * (Wsl[(0 * F + k) * F + c] + Wsl[(1 * F + k) * F + c] +
                             Wsl[(2 * F + k) * F + c] + Wsl[(3 * F + k) * F + c]);
            } else {
                int t = (k - F) >> 7;
                int kk = (k - F) & (F - 1);
                v = 0.25f * Wnl[((size_t)t * F + kk) * F + c];
            }
            _Float16 hh = (_Float16)v;
            oh[j] = __builtin_bit_cast(unsigned short, hh);
            ol[j] = f2h(v - (float)hh);
        }
    } else {
        int k = idx - 2 * perLayer;
        if (k < 2 * F) {
            int l = k >> 7;
            int j = k & (F - 1);
            const float* bl = l ? b2 : b1;
            bavg[k] = 0.25f * (bl[j] + bl[F + j] + bl[2 * F + j] + bl[3 * F + j]);
        }
    }
}

// ---- cast x fp32 -> fp16 ----
__global__ __launch_bounds__(256) void cast_x(
    const float* __restrict__ x, unsigned short* __restrict__ x16)
{
    int i = blockIdx.x * 256 + threadIdx.x;
    if (i < N_NODES * 64) {
        float2 v = ((const float2*)x)[i];
        ((unsigned*)x16)[i] = pack2h(v.x, v.y);
    }
}

// ---------------- CSR build: seg = dst*4 + t ----------------
__global__ __launch_bounds__(256) void hist_kernel(
    const int* __restrict__ dstA, const int* __restrict__ typA, int* __restrict__ counts)
{
    int e = blockIdx.x * 256 + threadIdx.x;
    if (e < N_EDGES) atomicAdd(&counts[dstA[e] * NT + typA[e]], 1);
}

__global__ __launch_bounds__(256) void scan1(int* __restrict__ counts, int* __restrict__ bsum)
{
    __shared__ int sh[256];
    int t = threadIdx.x;
    int base = blockIdx.x * 1024 + t * 4;
    int v[4];
    int tot = 0;
#pragma unroll
    for (int j = 0; j < 4; ++j) {
        int i = base + j;
        v[j] = (i < N_SEG) ? counts[i] : 0;
        tot += v[j];
    }
    sh[t] = tot;
    __syncthreads();
    for (int ofs = 1; ofs < 256; ofs <<= 1) {
        int add = (t >= ofs) ? sh[t - ofs] : 0;
        __syncthreads();
        sh[t] += add;
        __syncthreads();
    }
    int excl = (t > 0) ? sh[t - 1] : 0;
    if (t == 255) bsum[blockIdx.x] = sh[255];
#pragma unroll
    for (int j = 0; j < 4; ++j) {
        int i = base + j;
        if (i < N_SEG) counts[i] = excl;
        excl += v[j];
    }
}

__global__ __launch_bounds__(256) void scan2(int* __restrict__ bsum)
{
    __shared__ int sh[256];
    int t = threadIdx.x;
    sh[t] = (t < SCAN_BLK) ? bsum[t] : 0;
    __syncthreads();
    for (int ofs = 1; ofs < 256; ofs <<= 1) {
        int add = (t >= ofs) ? sh[t - ofs] : 0;
        __syncthreads();
        sh[t] += add;
        __syncthreads();
    }
    int excl = (t > 0) ? sh[t - 1] : 0;
    if (t < SCAN_BLK) bsum[t] = excl;
}

// finalize offsets in place; sentinel off[N_SEG] = N_EDGES
__global__ __launch_bounds__(256) void scan3(
    int* __restrict__ counts, const int* __restrict__ bsum, int* __restrict__ cursor)
{
    int i = blockIdx.x * 256 + threadIdx.x;
    if (i < N_SEG) {
        int v = counts[i] + bsum[i >> 10];
        counts[i] = v;
        cursor[i] = v;
    }
    if (i == 0) counts[N_SEG] = N_EDGES;
}

// permute: bucket-sorted edges; payload = (fp32 scale bits << 32) | dword-offset into Z
__global__ __launch_bounds__(256) void permute_kernel(
    const int* __restrict__ srcA, const int* __restrict__ dstA, const int* __restrict__ typA,
    const int* __restrict__ off, int* __restrict__ cursor,
    unsigned long long* __restrict__ perm64)
{
    int e = blockIdx.x * 256 + threadIdx.x;
    if (e < N_EDGES) {
        int t = typA[e];
        int seg = dstA[e] * NT + t;
        int pos = atomicAdd(&cursor[seg], 1);
        float inv = 1.0f / fmaxf((float)(off[seg + 1] - off[seg]), 1.0f);
        unsigned offw = (unsigned)(srcA[e] * 320 + (t + 1) * 64);  // dword offset
        perm64[pos] = ((unsigned long long)__float_as_uint(inv) << 32) | offw;
    }
}

// ---- dense transform: Z[N,640] bf16 = Hin[N,128] fp16 @ B[640? -> 5 planes x 128] ----
// A staged ONCE per 64-row block; 5 output planes looped; 2 barriers total.
__global__ __launch_bounds__(256) void gemm_z(
    const unsigned short* __restrict__ Hin,
    const unsigned short* __restrict__ Wh,
    const unsigned short* __restrict__ Wl,
    unsigned short* __restrict__ Z)
{
    __shared__ unsigned short AS[64][136];

    const int tid = threadIdx.x;
    const int lane = tid & 63;
    const int w = tid >> 6;
    const int quad = lane >> 4;
    const int l15 = lane & 15;
    const int nodeBase = blockIdx.x * 64;

    {
        int r = tid >> 2;
        int cb = (tid & 3) * 32;
        int n = nodeBase + r;
        int nc = n < N_NODES ? n : N_NODES - 1;
        const unsigned short* srcp = Hin + (size_t)nc * F + cb;
        *(uint4*)&AS[r][cb]      = *(const uint4*)(srcp);
        *(uint4*)&AS[r][cb + 8]  = *(const uint4*)(srcp + 8);
        *(uint4*)&AS[r][cb + 16] = *(const uint4*)(srcp + 16);
        *(uint4*)&AS[r][cb + 24] = *(const uint4*)(srcp + 24);
    }
    __syncthreads();

    const f16x8* BH = (const f16x8*)Wh;
    const f16x8* BL = (const f16x8*)Wl;

#pragma unroll 1
    for (int cp = 0; cp < 5; ++cp) {
        f32x4 acc[4][2];
#pragma unroll
        for (int rt = 0; rt < 4; ++rt)
#pragma unroll
            for (int ci = 0; ci < 2; ++ci)
                acc[rt][ci] = (f32x4){0.f, 0.f, 0.f, 0.f};

#pragma unroll
        for (int kt = 0; kt < 4; ++kt) {
            f16x8 bh[2], bl[2];
#pragma unroll
            for (int ci = 0; ci < 2; ++ci) {
                int fi = ((cp * 4 + kt) * NCT + (w * 2 + ci)) * 64 + lane;
                bh[ci] = BH[fi];
                bl[ci] = BL[fi];
            }
            f16x8 ah[4];
#pragma unroll
            for (int rt = 0; rt < 4; ++rt)
                ah[rt] = *(const f16x8*)&AS[rt * 16 + l15][kt * 32 + quad * 8];
#pragma unroll
            for (int rt = 0; rt < 4; ++rt)
#pragma unroll
                for (int ci = 0; ci < 2; ++ci) {
                    acc[rt][ci] = __builtin_amdgcn_mfma_f32_16x16x32_f16(ah[rt], bh[ci], acc[rt][ci], 0, 0, 0);
                    acc[rt][ci] = __builtin_amdgcn_mfma_f32_16x16x32_f16(ah[rt], bl[ci], acc[rt][ci], 0, 0, 0);
                }
        }

#pragma unroll
        for (int rt = 0; rt < 4; ++rt)
#pragma unroll
            for (int rr = 0; rr < 4; ++rr) {
                int row = rt * 16 + quad * 4 + rr;
                int n = nodeBase + row;
                if (n < N_NODES) {
                    size_t b = (size_t)n * 640 + cp * 128 + w * 32;
                    Z[b + l15]      = f2b(acc[rt][0][rr]);
                    Z[b + 16 + l15] = f2b(acc[rt][1][rr]);
                }
            }
    }
}

// ---- finalize: out[n] = selfZ + sum_e s_e * Z[src_e, plane t_e] + bias (+norm/relu) ----
// 8 nodes per wave; perm64 prefetched 64-deep (batch-aligned single buffer);
// self rows prefetched; scalar running-boundary flush; 16-deep gather pipeline.
#define FLUSH_NODE() do {                                                     \
    int n_ = n0 + cur;                                                        \
    float vx_ = __uint_as_float(sv[0] << 16) + accx + bv.x;                   \
    float vy_ = __uint_as_float(sv[0] & 0xffff0000u) + accy + bv.y;           \
    if (doNormRelu) {                                                         \
        float s_ = vx_ * vx_ + vy_ * vy_;                                     \
        s_ += __shfl_xor(s_, 1);  s_ += __shfl_xor(s_, 2);                    \
        s_ += __shfl_xor(s_, 4);  s_ += __shfl_xor(s_, 8);                    \
        s_ += __shfl_xor(s_, 16); s_ += __shfl_xor(s_, 32);                   \
        float sc_ = 1.0f / fmaxf(sqrtf(s_), 1e-12f);                          \
        vx_ = fmaxf(vx_ * sc_, 0.f);                                          \
        vy_ = fmaxf(vy_ * sc_, 0.f);                                          \
        ((unsigned*)outH)[(size_t)n_ * 64 + lane] = pack2h(vx_, vy_);         \
    } else {                                                                  \
        ((float2*)outF)[(size_t)n_ * 64 + lane] = make_float2(vx_, vy_);      \
    }                                                                         \
    _Pragma("unroll")                                                         \
    for (int q_ = 0; q_ < 7; ++q_) sv[q_] = sv[q_ + 1];                       \
} while (0)

__global__ __launch_bounds__(256) void finalize(
    const unsigned short* __restrict__ Z,
    const unsigned long long* __restrict__ perm64,
    const int* __restrict__ off,              // [N_SEG+1], sentinel = N_EDGES
    const float* __restrict__ bias,
    float* __restrict__ outF,                 // fp32 output (layer 2)
    unsigned short* __restrict__ outH,        // fp16 output (layer 1: norm+relu)
    int doNormRelu)
{
    const int lane = threadIdx.x & 63;
    const int w = threadIdx.x >> 6;
    const int n0 = (blockIdx.x * 4 + w) * 8;
    if (n0 >= N_NODES) return;

    const unsigned* Z32 = (const unsigned*)Z;
    const uint2* P = (const uint2*)perm64;

    // 9 node boundaries in a lane vector (node k start = off[(n0+k)*4])
    int bl = lane < 8 ? lane : 8;
    int vb = off[(n0 + bl) * 4];

    float2 bv = ((const float2*)bias)[lane];

    // prefetch self rows (plane 0) for the 8 nodes
    unsigned sv[8];
#pragma unroll
    for (int i = 0; i < 8; ++i)
        sv[i] = Z32[(size_t)(n0 + i) * 320 + lane];

    int s0   = __builtin_amdgcn_readfirstlane(vb);
    int eend = __builtin_amdgcn_readlane(vb, 8);

    // perm prefetch: batches advance by 16 from s0, so window [pbase, pbase+64)
    // always contains the current batch; P1 is the lookahead window.
    int pbase = s0;
    int i0 = pbase + lane;          i0 = i0 < N_EDGES - 1 ? i0 : N_EDGES - 1;
    int i1 = pbase + 64 + lane;     i1 = i1 < N_EDGES - 1 ? i1 : N_EDGES - 1;
    uint2 P0 = P[i0];
    uint2 P1 = P[i1];

    int cur = 0;
    int nextB = __builtin_amdgcn_readlane(vb, 1);
    float accx = 0.f, accy = 0.f;

    for (int e = s0; e < eend; e += 16) {
        if (e - pbase >= 64) {
            pbase += 64;
            P0 = P1;
            int i2 = pbase + 64 + lane;
            i2 = i2 < N_EDGES - 1 ? i2 : N_EDGES - 1;
            P1 = P[i2];
        }
        int nb = eend - e;
        if (nb > 16) nb = 16;

        unsigned uvv[16];
        float sc[16];
#pragma unroll
        for (int j = 0; j < 16; ++j) {
            if (j < nb) {
                int idx = e + j - pbase;   // always 0..63 (batch-aligned window)
                unsigned ow = (unsigned)__builtin_amdgcn_readlane((int)P0.x, idx);
                sc[j] = __uint_as_float((unsigned)__builtin_amdgcn_readlane((int)P0.y, idx));
                uvv[j] = Z32[(size_t)ow + lane];
            }
        }
#pragma unroll
        for (int j = 0; j < 16; ++j) {
            if (j < nb) {
                int ge = e + j;
                while (ge >= nextB) {
                    FLUSH_NODE();
                    accx = 0.f; accy = 0.f;
                    cur++;
                    nextB = __builtin_amdgcn_readlane(vb, cur + 1 < 8 ? cur + 1 : 8);
                }
                accx = fmaf(__uint_as_float(uvv[j] << 16), sc[j], accx);
                accy = fmaf(__uint_as_float(uvv[j] & 0xffff0000u), sc[j], accy);
            }
        }
    }
    while (cur < 8) {
        FLUSH_NODE();
        accx = 0.f; accy = 0.f;
        cur++;
    }
}

extern "C" void kernel_launch(void* const* d_in, const int* in_sizes, int n_in,
                              void* d_out, int out_size, void* d_ws, size_t ws_size,
                              hipStream_t stream)
{
    const float* x   = (const float*)d_in[0];
    const float* Ws1 = (const float*)d_in[1];
    const float* Wn1 = (const float*)d_in[2];
    const float* b1  = (const float*)d_in[3];
    const float* Ws2 = (const float*)d_in[4];
    const float* Wn2 = (const float*)d_in[5];
    const float* b2  = (const float*)d_in[6];
    const int* edge_index = (const int*)d_in[7];
    const int* edge_type  = (const int*)d_in[8];

    const int* srcA = edge_index;
    const int* dstA = edge_index + N_EDGES;

    // workspace layout (perm64 kept 8B-aligned; total ~97 MB as in round-0)
    unsigned short* Z   = (unsigned short*)d_ws;             // N*640 u16 = 64 MB
    unsigned short* x16 = Z + (size_t)N_NODES * 640;         // N*128 u16
    unsigned short* h1  = x16 + (size_t)N_NODES * F;         // N*128 u16
    unsigned short* Wh  = h1 + (size_t)N_NODES * F;          // 2*WELEM u16
    unsigned short* Wl  = Wh + (size_t)2 * WELEM;            // 2*WELEM u16
    float* bavg = (float*)(Wl + (size_t)2 * WELEM);          // 256 f32
    int* counts = (int*)(bavg + 2 * F);                      // N_SEG+2 (off + sentinel + pad)
    int* cursor = counts + (N_SEG + 2);                      // N_SEG
    int* bsum   = cursor + N_SEG;                            // 256
    unsigned long long* perm64 = (unsigned long long*)(bsum + 256);  // N_EDGES u64
    int* off = counts;                                       // alias after scan3

    // weights + bias + fp16 cast of x
    hipLaunchKernelGGL(build_w, dim3(81), dim3(256), 0, stream,
                       Ws1, Wn1, b1, Ws2, Wn2, b2, Wh, Wl, bavg);
    hipLaunchKernelGGL(cast_x, dim3((N_NODES * 64 + 255) / 256), dim3(256), 0, stream,
                       x, x16);

    // CSR build (shared by both layers)
    hipMemsetAsync(counts, 0, (size_t)N_SEG * sizeof(int), stream);
    hipLaunchKernelGGL(hist_kernel, dim3((N_EDGES + 255) / 256), dim3(256), 0, stream,
                       dstA, edge_type, counts);
    hipLaunchKernelGGL(scan1, dim3(SCAN_BLK), dim3(256), 0, stream, counts, bsum);
    hipLaunchKernelGGL(scan2, dim3(1), dim3(256), 0, stream, bsum);
    hipLaunchKernelGGL(scan3, dim3((N_SEG + 255) / 256), dim3(256), 0, stream,
                       counts, bsum, cursor);
    hipLaunchKernelGGL(permute_kernel, dim3((N_EDGES + 255) / 256), dim3(256), 0, stream,
                       srcA, dstA, edge_type, off, cursor, perm64);

    const int gemmGrid = (N_NODES + 63) / 64;     // 782
    const int finGrid  = (N_NODES + 31) / 32;     // 1563

    // ---------- layer 1 ----------
    hipLaunchKernelGGL(gemm_z, dim3(gemmGrid), dim3(256), 0, stream,
                       x16, Wh, Wl, Z);
    hipLaunchKernelGGL(finalize, dim3(finGrid), dim3(256), 0, stream,
                       Z, perm64, off, bavg, (float*)nullptr, h1, 1);

    // ---------- layer 2 ----------
    hipLaunchKernelGGL(gemm_z, dim3(gemmGrid), dim3(256), 0, stream,
                       h1, Wh + WELEM, Wl + WELEM, Z);
    hipLaunchKernelGGL(finalize, dim3(finGrid), dim3(256), 0, stream,
                       Z, perm64, off, bavg + F, (float*)d_out,
                       (unsigned short*)nullptr, 0);
}